// Round 7
// baseline (795.904 us; speedup 1.0000x reference)
//
#include <hip/hip_runtime.h>
#include <hip/hip_bf16.h>

typedef __attribute__((ext_vector_type(4))) float f32x4;
typedef __attribute__((ext_vector_type(8))) short s16x8;
typedef __attribute__((ext_vector_type(4))) unsigned short u16x4;
typedef __attribute__((ext_vector_type(8))) unsigned short u16x8;
typedef __attribute__((ext_vector_type(4))) int i32x4;

#define NB 64
#define NS 256
#define ND 2048
#define NH 16
#define NHD 128

__device__ __forceinline__ unsigned short f2bf(float f){
  unsigned int u = __float_as_uint(f);
  u += 0x7fffu + ((u >> 16) & 1u);
  return (unsigned short)(u >> 16);
}

__device__ __forceinline__ void gload16(const void* g, void* l){
  __builtin_amdgcn_global_load_lds(
    (const __attribute__((address_space(1))) unsigned int*)g,
    (__attribute__((address_space(3))) unsigned int*)l, 16, 0, 0);
}

#define SBAR()  __builtin_amdgcn_sched_barrier(0)
#define BARRIER() do{ SBAR(); __builtin_amdgcn_s_barrier(); SBAR(); }while(0)
#define WAIT_LGKM0() do{ asm volatile("s_waitcnt lgkmcnt(0)" ::: "memory"); SBAR(); }while(0)
#define WAIT_VM0()   do{ asm volatile("s_waitcnt vmcnt(0)"   ::: "memory"); SBAR(); }while(0)
#define WAIT_VM8()   do{ asm volatile("s_waitcnt vmcnt(8)"   ::: "memory"); SBAR(); }while(0)

// ---------------- fp32 -> bf16 conversion ----------------
__global__ __launch_bounds__(256) void wconv(const float* __restrict__ s,
                                             unsigned short* __restrict__ d, int n8){
  int i = blockIdx.x*256 + threadIdx.x;
  if (i >= n8) return;
  f32x4 a = *(const f32x4*)(s + (size_t)i*8);
  f32x4 b = *(const f32x4*)(s + (size_t)i*8 + 4);
  u16x8 u;
  #pragma unroll
  for (int r=0;r<4;r++){ u[r]=f2bf(a[r]); u[4+r]=f2bf(b[r]); }
  *(u16x8*)(d + (size_t)i*8) = u;
}

// ---------------- 256x256 8-phase GEMM: C = A(bf16) @ W^T(bf16) + bias ----------------
// Round-7 change: all 4 prefetch STAGEs issued at the FIRST phase of each
// half-iteration (target dbuf provably dead since the previous switch barrier);
// drains (vmcnt(0)) unchanged at each buffer switch. Phases 3+4 merged into one
// 32-MFMA register-only cluster.
template<int OUTMODE>
__global__ __launch_bounds__(512, 2) void gemm256(
    const unsigned short* __restrict__ A, const unsigned short* __restrict__ Bw,
    const float* __restrict__ bias, void* __restrict__ Out, int m_base)
{
  extern __shared__ __attribute__((aligned(16))) char ldsb[];  // 131072 B
  const int tid  = threadIdx.x;
  const int lane = tid & 63, wid = tid >> 6;
  const int g = lane >> 4, l15 = lane & 15;
  const int wm = wid >> 2, wn = wid & 3;

  const int nwg = gridDim.x, bid = blockIdx.x;
  const int swz = (bid & 7) * (nwg >> 3) + (bid >> 3);
  const int mt = swz >> 3, nt = swz & 7;
  const int m0 = mt*256, n0 = nt*256;

  const int srow_l = tid >> 3;
  const int scol   = (((tid & 7) ^ (srow_l & 7)) * 8);
  const unsigned short* gsrc[4];
  gsrc[0] = A  + (size_t)(m0 +       srow_l)*ND + scol;
  gsrc[1] = A  + (size_t)(m0 + 128 + srow_l)*ND + scol;
  gsrc[2] = Bw + (size_t)(n0 +       srow_l)*ND + scol;
  gsrc[3] = Bw + (size_t)(n0 + 128 + srow_l)*ND + scol;

#define STAGE(buf, p, kt) do{ \
    const unsigned short* s_ = gsrc[p] + (kt); \
    char* d_ = ldsb + (buf)*65536 + ((p)>>1)*32768 + ((p)&1)*16384 + tid*16; \
    gload16(s_, d_); gload16(s_ + (size_t)64*ND, d_ + 8192); }while(0)

#define RD_A(buf, qa) do{ \
    _Pragma("unroll") for (int i_=0;i_<4;i_++){ \
      int hr = (qa)*64 + i_*16 + l15; \
      const char* p_ = ldsb + (buf)*65536 + wm*16384 + hr*128; \
      _Pragma("unroll") for (int ks_=0;ks_<2;ks_++) \
        av[i_][ks_] = *(const s16x8*)(p_ + (((ks_*4+g) ^ (hr&7))*16)); } }while(0)

#define RD_B(buf, dst, qb) do{ \
    _Pragma("unroll") for (int j_=0;j_<2;j_++){ \
      int hc = (wn&1)*64 + (qb)*32 + j_*16 + l15; \
      const char* p_ = ldsb + (buf)*65536 + 32768 + (wn>>1)*16384 + hc*128; \
      _Pragma("unroll") for (int ks_=0;ks_<2;ks_++) \
        dst[j_][ks_] = *(const s16x8*)(p_ + (((ks_*4+g) ^ (hc&7))*16)); } }while(0)

#define MFMA_PH(qa, qb, bv) do{ \
    __builtin_amdgcn_s_setprio(1); \
    _Pragma("unroll") for (int i_=0;i_<4;i_++) \
      _Pragma("unroll") for (int j_=0;j_<2;j_++) \
        _Pragma("unroll") for (int ks_=0;ks_<2;ks_++) \
          acc[(qa)*4+i_][(qb)*2+j_] = __builtin_amdgcn_mfma_f32_16x16x32_bf16( \
              av[i_][ks_], bv[j_][ks_], acc[(qa)*4+i_][(qb)*2+j_], 0,0,0); \
    __builtin_amdgcn_s_setprio(0); }while(0)

  f32x4 acc[8][4];
  s16x8 av[4][2], bva[2][2], bvb[2][2];

  STAGE(0,0,0); STAGE(0,1,0); STAGE(0,2,0); STAGE(0,3,0);
  #pragma unroll
  for (int i=0;i<8;i++)
    #pragma unroll
    for (int j=0;j<4;j++) acc[i][j] = f32x4{0.f,0.f,0.f,0.f};
  WAIT_VM0();
  BARRIER();

  for (int t = 0; t < 16; ++t) {
    const int kt1 = t*128 + 64, kt2 = t*128 + 128;
    // ---- half A: compute dbuf0 (tile 2t); prefetch tile 2t+1 -> dbuf1 (issue-early)
    RD_A(0,0); RD_B(0,bva,0);
    STAGE(1,0,kt1); STAGE(1,1,kt1); STAGE(1,2,kt1); STAGE(1,3,kt1);
    BARRIER(); WAIT_LGKM0();
    MFMA_PH(0,0,bva);
    BARRIER();
    RD_B(0,bvb,1);
    BARRIER(); WAIT_LGKM0();
    MFMA_PH(0,1,bvb);
    BARRIER();
    RD_A(0,1);
    BARRIER(); WAIT_LGKM0();
    MFMA_PH(1,0,bva);
    MFMA_PH(1,1,bvb);
    WAIT_VM0();
    BARRIER();
    // ---- half B: compute dbuf1 (tile 2t+1); prefetch tile 2t+2 -> dbuf0
    RD_A(1,0); RD_B(1,bva,0);
    if (t < 15){ STAGE(0,0,kt2); STAGE(0,1,kt2); STAGE(0,2,kt2); STAGE(0,3,kt2); }
    BARRIER(); WAIT_LGKM0();
    MFMA_PH(0,0,bva);
    BARRIER();
    RD_B(1,bvb,1);
    BARRIER(); WAIT_LGKM0();
    MFMA_PH(0,1,bvb);
    BARRIER();
    RD_A(1,1);
    BARRIER(); WAIT_LGKM0();
    MFMA_PH(1,0,bva);
    MFMA_PH(1,1,bvb);
    WAIT_VM0();
    BARRIER();
  }

  #pragma unroll
  for (int jx=0;jx<4;jx++){
    int n = n0 + wn*64 + ((jx>>1)<<5) + ((jx&1)<<4) + l15;
    float bj = bias[n];
    #pragma unroll
    for (int i=0;i<8;i++){
      int mb = m_base + m0 + wm*128 + ((i>>2)<<6) + ((i&3)<<4) + g*4;
      if (OUTMODE == 2){
        float* O = (float*)Out;
        #pragma unroll
        for (int r=0;r<4;r++) O[(size_t)(mb+r)*ND + n] = acc[i][jx][r] + bj;
      } else if (OUTMODE == 0){
        unsigned short* O = (unsigned short*)Out;
        int bb = mb >> 8, h = n >> 7, d = n & 127, s0 = mb & 255;
        #pragma unroll
        for (int r=0;r<4;r++)
          O[(((size_t)bb*NH + h)*NS + s0 + r)*NHD + d] = f2bf(acc[i][jx][r] + bj);
      } else {
        unsigned short* O = (unsigned short*)Out;
        int bb = mb >> 8, h = n >> 7, d = n & 127, s0 = mb & 255;
        u16x4 u;
        #pragma unroll
        for (int r=0;r<4;r++) u[r] = f2bf(acc[i][jx][r] + bj);
        *(u16x4*)(O + (((size_t)bb*NH + h)*NHD + d)*NS + s0) = u;
      }
    }
  }
#undef STAGE
#undef RD_A
#undef RD_B
#undef MFMA_PH
}

// ---------------- fused attention v2 (unchanged from round 6) ----------------
__global__ __launch_bounds__(512, 1) void attn_fused2(
  const unsigned short* __restrict__ Qh, const unsigned short* __restrict__ Kh,
  const unsigned short* __restrict__ VT, const int* __restrict__ mask,
  const float* __restrict__ bias_table, unsigned short* __restrict__ AO)
{
  __shared__ unsigned short Klds[256*128];
  __shared__ unsigned short Vlds[128*256];
  char* Kb_ = (char*)Klds; char* Vb_ = (char*)Vlds;
  const int bh = blockIdx.x, b = bh >> 4, h = bh & 15;
  const int tid = threadIdx.x, lane = tid & 63, w = tid >> 6;
  const int g = lane >> 4, l15 = lane & 15;

  {
    const unsigned short* Ksrc = Kh + (size_t)bh*NS*NHD;
    int r0 = tid >> 4, sl = tid & 15;
    #pragma unroll
    for (int c=0;c<8;c++){
      int row = c*32 + r0;
      gload16(Ksrc + (size_t)row*NHD + ((sl ^ (row&7))*8), Kb_ + c*8192 + tid*16);
    }
  }
  {
    const unsigned short* Vsrc = VT + (size_t)bh*NHD*NS;
    int r0 = tid >> 5, sl = tid & 31;
    #pragma unroll
    for (int c=0;c<8;c++){
      int row = c*16 + r0;
      gload16(Vsrc + (size_t)row*NS + ((sl ^ (row&7))*8), Vb_ + c*8192 + tid*16);
    }
  }
  WAIT_VM8();
  BARRIER();

  const float scale = 0.08838834764831845f;
  const int* mrow = mask + b*NS;
  const int s0l = l15 + ((g&1)<<5), s1l = s0l + 16;
  const int sel = g >> 1;

  auto pass = [&](int p, bool wait_v){
    const int q = w*32 + p*16 + l15;
    const unsigned short* Qrow = Qh + ((size_t)bh*NS + q)*NHD;
    s16x8 bq[4];
    #pragma unroll
    for (int kk=0;kk<4;kk++) bq[kk] = *(const s16x8*)(Qrow + kk*32 + g*8);

    f32x4 c[16];
    __builtin_amdgcn_s_setprio(1);
    #pragma unroll
    for (int kb=0;kb<16;kb++){
      c[kb] = f32x4{0.f,0.f,0.f,0.f};
      int row = kb*16 + l15;
      #pragma unroll
      for (int kk=0;kk<4;kk++){
        s16x8 a = *(const s16x8*)(Kb_ + row*256 + (((kk*4+g) ^ (row&7))*16));
        c[kb] = __builtin_amdgcn_mfma_f32_16x16x32_bf16(a, bq[kk], c[kb], 0,0,0);
      }
    }
    __builtin_amdgcn_s_setprio(0);

    const float* brow = bias_table + ((size_t)h*NS + q)*NS;
    float mx = -3.0e38f;
    #pragma unroll
    for (int kb=0;kb<16;kb++){
      f32x4 b4 = *(const f32x4*)(brow + kb*16 + g*4);
      i32x4 m4 = *(const i32x4*)(mrow + kb*16 + g*4);
      #pragma unroll
      for (int r=0;r<4;r++){
        float val = (m4[r] != 0) ? (c[kb][r]*scale + b4[r]) : -3.0e38f;
        c[kb][r] = val;
        mx = fmaxf(mx, val);
      }
    }
    mx = fmaxf(mx, __shfl_xor(mx, 16));
    mx = fmaxf(mx, __shfl_xor(mx, 32));
    float sum = 0.f;
    #pragma unroll
    for (int kb=0;kb<16;kb++)
      #pragma unroll
      for (int r=0;r<4;r++){
        float pv = __expf(c[kb][r] - mx);
        c[kb][r] = pv; sum += pv;
      }
    sum += __shfl_xor(sum, 16);
    sum += __shfl_xor(sum, 32);
    float inv = 1.f / sum;

    unsigned int pk[16][2];
    #pragma unroll
    for (int kb=0;kb<16;kb++){
      pk[kb][0] = (unsigned int)f2bf(c[kb][0]*inv) | ((unsigned int)f2bf(c[kb][1]*inv) << 16);
      pk[kb][1] = (unsigned int)f2bf(c[kb][2]*inv) | ((unsigned int)f2bf(c[kb][3]*inv) << 16);
    }

    if (wait_v){ WAIT_VM0(); BARRIER(); }

    s16x8 pb[8];
    #pragma unroll
    for (int kk=0;kk<8;kk++){
      unsigned int e0 = (unsigned int)__shfl((int)pk[2*kk][0],   s0l);
      unsigned int e1 = (unsigned int)__shfl((int)pk[2*kk][1],   s0l);
      unsigned int e2 = (unsigned int)__shfl((int)pk[2*kk][0],   s1l);
      unsigned int e3 = (unsigned int)__shfl((int)pk[2*kk][1],   s1l);
      unsigned int o0 = (unsigned int)__shfl((int)pk[2*kk+1][0], s0l);
      unsigned int o1 = (unsigned int)__shfl((int)pk[2*kk+1][1], s0l);
      unsigned int o2 = (unsigned int)__shfl((int)pk[2*kk+1][0], s1l);
      unsigned int o3 = (unsigned int)__shfl((int)pk[2*kk+1][1], s1l);
      union { unsigned int wd[4]; s16x8 v; } u_;
      u_.wd[0] = sel ? o0 : e0; u_.wd[1] = sel ? o1 : e1;
      u_.wd[2] = sel ? o2 : e2; u_.wd[3] = sel ? o3 : e3;
      pb[kk] = u_.v;
    }

    f32x4 oacc[8];
    __builtin_amdgcn_s_setprio(1);
    #pragma unroll
    for (int dt=0;dt<8;dt++){
      oacc[dt] = f32x4{0.f,0.f,0.f,0.f};
      int row = dt*16 + l15;
      #pragma unroll
      for (int kk=0;kk<8;kk++){
        s16x8 a = *(const s16x8*)(Vb_ + row*512 + (((kk*4+g) ^ (row&7))*16));
        oacc[dt] = __builtin_amdgcn_mfma_f32_16x16x32_bf16(a, pb[kk], oacc[dt], 0,0,0);
      }
    }
    __builtin_amdgcn_s_setprio(0);

    #pragma unroll
    for (int dt=0;dt<8;dt++){
      u16x4 u;
      #pragma unroll
      for (int r=0;r<4;r++) u[r] = f2bf(oacc[dt][r]);
      *(u16x4*)(AO + ((size_t)b*NS + q)*ND + h*NHD + dt*16 + g*4) = u;
    }
  };

  pass(0, true);
  pass(1, false);
}

extern "C" void kernel_launch(void* const* d_in, const int* in_sizes, int n_in,
                              void* d_out, int out_size, void* d_ws, size_t ws_size,
                              hipStream_t stream)
{
  const float* q  = (const float*)d_in[0];
  const float* k  = (const float*)d_in[1];
  const float* v  = (const float*)d_in[2];
  const int* mask = (const int*)d_in[3];
  const float* Wq = (const float*)d_in[4];
  const float* bq = (const float*)d_in[5];
  const float* Wk = (const float*)d_in[6];
  const float* bk = (const float*)d_in[7];
  const float* Wv = (const float*)d_in[8];
  const float* bv = (const float*)d_in[9];
  const float* Wo = (const float*)d_in[10];
  const float* bo = (const float*)d_in[11];
  const float* bias_table = (const float*)d_in[12];

  // workspace layout, max 336 MiB (< proven 352 MiB):
  //   Wob [0,8M)  wb [8M,16M)  tmp [16M,80M) (full-M bf16 activations)
  //   Qh [80M,144M)  Kh [144M,208M)  VT [208M,272M)  AO [272M,336M)
  char* ws = (char*)d_ws;
  unsigned short* Wob = (unsigned short*)(ws + 0);
  unsigned short* wb  = (unsigned short*)(ws + 8388608);
  unsigned short* tmp = (unsigned short*)(ws + 16777216);
  unsigned short* Qh  = (unsigned short*)(ws + 83886080);
  unsigned short* Kh  = (unsigned short*)(ws + 150994944);
  unsigned short* VT  = (unsigned short*)(ws + 218103808);
  unsigned short* AO  = (unsigned short*)(ws + 285212672);

  hipFuncSetAttribute((const void*)gemm256<0>, hipFuncAttributeMaxDynamicSharedMemorySize, 131072);
  hipFuncSetAttribute((const void*)gemm256<1>, hipFuncAttributeMaxDynamicSharedMemorySize, 131072);
  hipFuncSetAttribute((const void*)gemm256<2>, hipFuncAttributeMaxDynamicSharedMemorySize, 131072);

  wconv<<<2048,256,0,stream>>>(Wo, Wob, 524288);

  const float* acts[3]  = {q, k, v};
  const float* wgt[3]   = {Wq, Wk, Wv};
  const float* bia[3]   = {bq, bk, bv};
  unsigned short* outs[3] = {Qh, Kh, VT};

  for (int x = 0; x < 3; ++x) {
    wconv<<<2048,256,0,stream>>>(wgt[x], wb, 524288);
    wconv<<<16384,256,0,stream>>>(acts[x], tmp, 4194304);
    if (x < 2)
      gemm256<0><<<512,512,131072,stream>>>(tmp, wb, bia[x], outs[x], 0);
    else
      gemm256<1><<<512,512,131072,stream>>>(tmp, wb, bia[x], outs[x], 0);
  }

  attn_fused2<<<1024,512,0,stream>>>(Qh,Kh,VT,mask,bias_table,AO);
  gemm256<2><<<512,512,131072,stream>>>(AO,Wob,bo,(float*)d_out,0);
}

// Round 8
// 778.265 us; speedup vs baseline: 1.0227x; 1.0227x over previous
//
#include <hip/hip_runtime.h>
#include <hip/hip_bf16.h>

typedef __attribute__((ext_vector_type(4))) float f32x4;
typedef __attribute__((ext_vector_type(8))) short s16x8;
typedef __attribute__((ext_vector_type(4))) unsigned short u16x4;
typedef __attribute__((ext_vector_type(8))) unsigned short u16x8;
typedef __attribute__((ext_vector_type(4))) int i32x4;

#define NB 64
#define NS 256
#define ND 2048
#define NH 16
#define NHD 128

__device__ __forceinline__ unsigned short f2bf(float f){
  unsigned int u = __float_as_uint(f);
  u += 0x7fffu + ((u >> 16) & 1u);
  return (unsigned short)(u >> 16);
}

__device__ __forceinline__ void gload16(const void* g, void* l){
  __builtin_amdgcn_global_load_lds(
    (const __attribute__((address_space(1))) unsigned int*)g,
    (__attribute__((address_space(3))) unsigned int*)l, 16, 0, 0);
}

#define SBAR()  __builtin_amdgcn_sched_barrier(0)
#define BARRIER() do{ SBAR(); __builtin_amdgcn_s_barrier(); SBAR(); }while(0)
#define WAIT_LGKM0() do{ asm volatile("s_waitcnt lgkmcnt(0)" ::: "memory"); SBAR(); }while(0)
#define WAIT_VM0()   do{ asm volatile("s_waitcnt vmcnt(0)"   ::: "memory"); SBAR(); }while(0)
#define WAIT_VM8()   do{ asm volatile("s_waitcnt vmcnt(8)"   ::: "memory"); SBAR(); }while(0)

// ---------------- fp32 -> bf16 conversion ----------------
__global__ __launch_bounds__(256) void wconv(const float* __restrict__ s,
                                             unsigned short* __restrict__ d, int n8){
  int i = blockIdx.x*256 + threadIdx.x;
  if (i >= n8) return;
  f32x4 a = *(const f32x4*)(s + (size_t)i*8);
  f32x4 b = *(const f32x4*)(s + (size_t)i*8 + 4);
  u16x8 u;
  #pragma unroll
  for (int r=0;r<4;r++){ u[r]=f2bf(a[r]); u[4+r]=f2bf(b[r]); }
  *(u16x8*)(d + (size_t)i*8) = u;
}

// ---------------- 256x256 GEMM, counted-vmcnt pipeline ----------------
// Round-8: 2-tile-deep prefetch. Prologue stages tiles 0,1 (16 loads/thread
// in flight). Each half-iteration computes tile t from dbuf[t&1]; after its
// last ds_read completes (lgkmcnt(0) BEFORE the barrier -> overwrite provably
// safe), it stages tile t+2 into the same dbuf, overlapped with the final
// 32-MFMA cluster; the switch waits vmcnt(8) -- only tile t+1 must land,
// tile t+2's loads stay in flight across the barrier. No vmcnt(0) in-loop.
template<int OUTMODE>
__global__ __launch_bounds__(512, 2) void gemm256(
    const unsigned short* __restrict__ A, const unsigned short* __restrict__ Bw,
    const float* __restrict__ bias, void* __restrict__ Out, int m_base)
{
  extern __shared__ __attribute__((aligned(16))) char ldsb[];  // 131072 B
  const int tid  = threadIdx.x;
  const int lane = tid & 63, wid = tid >> 6;
  const int g = lane >> 4, l15 = lane & 15;
  const int wm = wid >> 2, wn = wid & 3;

  const int nwg = gridDim.x, bid = blockIdx.x;
  const int swz = (bid & 7) * (nwg >> 3) + (bid >> 3);
  const int mt = swz >> 3, nt = swz & 7;
  const int m0 = mt*256, n0 = nt*256;

  const int srow_l = tid >> 3;
  const int scol   = (((tid & 7) ^ (srow_l & 7)) * 8);
  const unsigned short* gsrc[4];
  gsrc[0] = A  + (size_t)(m0 +       srow_l)*ND + scol;
  gsrc[1] = A  + (size_t)(m0 + 128 + srow_l)*ND + scol;
  gsrc[2] = Bw + (size_t)(n0 +       srow_l)*ND + scol;
  gsrc[3] = Bw + (size_t)(n0 + 128 + srow_l)*ND + scol;

#define STAGE(buf, p, kt) do{ \
    const unsigned short* s_ = gsrc[p] + (kt); \
    char* d_ = ldsb + (buf)*65536 + ((p)>>1)*32768 + ((p)&1)*16384 + tid*16; \
    gload16(s_, d_); gload16(s_ + (size_t)64*ND, d_ + 8192); }while(0)

#define RD_A(buf, qa) do{ \
    _Pragma("unroll") for (int i_=0;i_<4;i_++){ \
      int hr = (qa)*64 + i_*16 + l15; \
      const char* p_ = ldsb + (buf)*65536 + wm*16384 + hr*128; \
      _Pragma("unroll") for (int ks_=0;ks_<2;ks_++) \
        av[i_][ks_] = *(const s16x8*)(p_ + (((ks_*4+g) ^ (hr&7))*16)); } }while(0)

#define RD_B(buf, dst, qb) do{ \
    _Pragma("unroll") for (int j_=0;j_<2;j_++){ \
      int hc = (wn&1)*64 + (qb)*32 + j_*16 + l15; \
      const char* p_ = ldsb + (buf)*65536 + 32768 + (wn>>1)*16384 + hc*128; \
      _Pragma("unroll") for (int ks_=0;ks_<2;ks_++) \
        dst[j_][ks_] = *(const s16x8*)(p_ + (((ks_*4+g) ^ (hc&7))*16)); } }while(0)

#define MFMA_PH(qa, qb, bv) do{ \
    __builtin_amdgcn_s_setprio(1); \
    _Pragma("unroll") for (int i_=0;i_<4;i_++) \
      _Pragma("unroll") for (int j_=0;j_<2;j_++) \
        _Pragma("unroll") for (int ks_=0;ks_<2;ks_++) \
          acc[(qa)*4+i_][(qb)*2+j_] = __builtin_amdgcn_mfma_f32_16x16x32_bf16( \
              av[i_][ks_], bv[j_][ks_], acc[(qa)*4+i_][(qb)*2+j_], 0,0,0); \
    __builtin_amdgcn_s_setprio(0); }while(0)

// one half-iteration: compute tile in dbuf `buf`; stage tile kt_next -> same buf
// doStage: 1 = stage + WAIT_VM8 ; 2 = no stage + WAIT_VM0 ; 3 = no stage, no wait
#define HALF(buf, kt_next, doStage) do{ \
    RD_A(buf,0); RD_B(buf,bva,0); \
    BARRIER(); WAIT_LGKM0(); \
    MFMA_PH(0,0,bva); \
    BARRIER(); \
    RD_B(buf,bvb,1); \
    BARRIER(); WAIT_LGKM0(); \
    MFMA_PH(0,1,bvb); \
    BARRIER(); \
    RD_A(buf,1); \
    WAIT_LGKM0(); BARRIER(); \
    if ((doStage)==1){ STAGE(buf,0,kt_next); STAGE(buf,1,kt_next); \
                       STAGE(buf,2,kt_next); STAGE(buf,3,kt_next); } \
    MFMA_PH(1,0,bva); \
    MFMA_PH(1,1,bvb); \
    if ((doStage)==1){ WAIT_VM8(); BARRIER(); } \
    else if ((doStage)==2){ WAIT_VM0(); BARRIER(); } \
  }while(0)

  f32x4 acc[8][4];
  s16x8 av[4][2], bva[2][2], bvb[2][2];

  // prologue: stage tile 0 -> dbuf0, tile 1 -> dbuf1 (16 loads in flight)
  STAGE(0,0,0); STAGE(0,1,0); STAGE(0,2,0); STAGE(0,3,0);
  STAGE(1,0,64); STAGE(1,1,64); STAGE(1,2,64); STAGE(1,3,64);
  #pragma unroll
  for (int i=0;i<8;i++)
    #pragma unroll
    for (int j=0;j<4;j++) acc[i][j] = f32x4{0.f,0.f,0.f,0.f};
  WAIT_VM8();    // tile 0 landed; tile 1 still in flight
  BARRIER();

  for (int t = 0; t < 15; ++t) {
    HALF(0, (2*t+2)*64, 1);   // tile 2t   ; stage 2t+2 -> dbuf0 ; wait tile 2t+1
    HALF(1, (2*t+3)*64, 1);   // tile 2t+1 ; stage 2t+3 -> dbuf1 ; wait tile 2t+2
  }
  HALF(0, 0, 2);              // tile 30 ; no stage ; wait ALL (tile 31 lands)
  HALF(1, 0, 3);              // tile 31 ; no stage ; no wait

  #pragma unroll
  for (int jx=0;jx<4;jx++){
    int n = n0 + wn*64 + ((jx>>1)<<5) + ((jx&1)<<4) + l15;
    float bj = bias[n];
    #pragma unroll
    for (int i=0;i<8;i++){
      int mb = m_base + m0 + wm*128 + ((i>>2)<<6) + ((i&3)<<4) + g*4;
      if (OUTMODE == 2){
        float* O = (float*)Out;
        #pragma unroll
        for (int r=0;r<4;r++) O[(size_t)(mb+r)*ND + n] = acc[i][jx][r] + bj;
      } else if (OUTMODE == 0){
        unsigned short* O = (unsigned short*)Out;
        int bb = mb >> 8, h = n >> 7, d = n & 127, s0 = mb & 255;
        #pragma unroll
        for (int r=0;r<4;r++)
          O[(((size_t)bb*NH + h)*NS + s0 + r)*NHD + d] = f2bf(acc[i][jx][r] + bj);
      } else {
        unsigned short* O = (unsigned short*)Out;
        int bb = mb >> 8, h = n >> 7, d = n & 127, s0 = mb & 255;
        u16x4 u;
        #pragma unroll
        for (int r=0;r<4;r++) u[r] = f2bf(acc[i][jx][r] + bj);
        *(u16x4*)(O + (((size_t)bb*NH + h)*NHD + d)*NS + s0) = u;
      }
    }
  }
#undef STAGE
#undef RD_A
#undef RD_B
#undef MFMA_PH
#undef HALF
}

// ---------------- fused attention v2 (unchanged from round 6) ----------------
__global__ __launch_bounds__(512, 1) void attn_fused2(
  const unsigned short* __restrict__ Qh, const unsigned short* __restrict__ Kh,
  const unsigned short* __restrict__ VT, const int* __restrict__ mask,
  const float* __restrict__ bias_table, unsigned short* __restrict__ AO)
{
  __shared__ unsigned short Klds[256*128];
  __shared__ unsigned short Vlds[128*256];
  char* Kb_ = (char*)Klds; char* Vb_ = (char*)Vlds;
  const int bh = blockIdx.x, b = bh >> 4, h = bh & 15;
  const int tid = threadIdx.x, lane = tid & 63, w = tid >> 6;
  const int g = lane >> 4, l15 = lane & 15;

  {
    const unsigned short* Ksrc = Kh + (size_t)bh*NS*NHD;
    int r0 = tid >> 4, sl = tid & 15;
    #pragma unroll
    for (int c=0;c<8;c++){
      int row = c*32 + r0;
      gload16(Ksrc + (size_t)row*NHD + ((sl ^ (row&7))*8), Kb_ + c*8192 + tid*16);
    }
  }
  {
    const unsigned short* Vsrc = VT + (size_t)bh*NHD*NS;
    int r0 = tid >> 5, sl = tid & 31;
    #pragma unroll
    for (int c=0;c<8;c++){
      int row = c*16 + r0;
      gload16(Vsrc + (size_t)row*NS + ((sl ^ (row&7))*8), Vb_ + c*8192 + tid*16);
    }
  }
  WAIT_VM8();
  BARRIER();

  const float scale = 0.08838834764831845f;
  const int* mrow = mask + b*NS;
  const int s0l = l15 + ((g&1)<<5), s1l = s0l + 16;
  const int sel = g >> 1;

  auto pass = [&](int p, bool wait_v){
    const int q = w*32 + p*16 + l15;
    const unsigned short* Qrow = Qh + ((size_t)bh*NS + q)*NHD;
    s16x8 bq[4];
    #pragma unroll
    for (int kk=0;kk<4;kk++) bq[kk] = *(const s16x8*)(Qrow + kk*32 + g*8);

    f32x4 c[16];
    __builtin_amdgcn_s_setprio(1);
    #pragma unroll
    for (int kb=0;kb<16;kb++){
      c[kb] = f32x4{0.f,0.f,0.f,0.f};
      int row = kb*16 + l15;
      #pragma unroll
      for (int kk=0;kk<4;kk++){
        s16x8 a = *(const s16x8*)(Kb_ + row*256 + (((kk*4+g) ^ (row&7))*16));
        c[kb] = __builtin_amdgcn_mfma_f32_16x16x32_bf16(a, bq[kk], c[kb], 0,0,0);
      }
    }
    __builtin_amdgcn_s_setprio(0);

    const float* brow = bias_table + ((size_t)h*NS + q)*NS;
    float mx = -3.0e38f;
    #pragma unroll
    for (int kb=0;kb<16;kb++){
      f32x4 b4 = *(const f32x4*)(brow + kb*16 + g*4);
      i32x4 m4 = *(const i32x4*)(mrow + kb*16 + g*4);
      #pragma unroll
      for (int r=0;r<4;r++){
        float val = (m4[r] != 0) ? (c[kb][r]*scale + b4[r]) : -3.0e38f;
        c[kb][r] = val;
        mx = fmaxf(mx, val);
      }
    }
    mx = fmaxf(mx, __shfl_xor(mx, 16));
    mx = fmaxf(mx, __shfl_xor(mx, 32));
    float sum = 0.f;
    #pragma unroll
    for (int kb=0;kb<16;kb++)
      #pragma unroll
      for (int r=0;r<4;r++){
        float pv = __expf(c[kb][r] - mx);
        c[kb][r] = pv; sum += pv;
      }
    sum += __shfl_xor(sum, 16);
    sum += __shfl_xor(sum, 32);
    float inv = 1.f / sum;

    unsigned int pk[16][2];
    #pragma unroll
    for (int kb=0;kb<16;kb++){
      pk[kb][0] = (unsigned int)f2bf(c[kb][0]*inv) | ((unsigned int)f2bf(c[kb][1]*inv) << 16);
      pk[kb][1] = (unsigned int)f2bf(c[kb][2]*inv) | ((unsigned int)f2bf(c[kb][3]*inv) << 16);
    }

    if (wait_v){ WAIT_VM0(); BARRIER(); }

    s16x8 pb[8];
    #pragma unroll
    for (int kk=0;kk<8;kk++){
      unsigned int e0 = (unsigned int)__shfl((int)pk[2*kk][0],   s0l);
      unsigned int e1 = (unsigned int)__shfl((int)pk[2*kk][1],   s0l);
      unsigned int e2 = (unsigned int)__shfl((int)pk[2*kk][0],   s1l);
      unsigned int e3 = (unsigned int)__shfl((int)pk[2*kk][1],   s1l);
      unsigned int o0 = (unsigned int)__shfl((int)pk[2*kk+1][0], s0l);
      unsigned int o1 = (unsigned int)__shfl((int)pk[2*kk+1][1], s0l);
      unsigned int o2 = (unsigned int)__shfl((int)pk[2*kk+1][0], s1l);
      unsigned int o3 = (unsigned int)__shfl((int)pk[2*kk+1][1], s1l);
      union { unsigned int wd[4]; s16x8 v; } u_;
      u_.wd[0] = sel ? o0 : e0; u_.wd[1] = sel ? o1 : e1;
      u_.wd[2] = sel ? o2 : e2; u_.wd[3] = sel ? o3 : e3;
      pb[kk] = u_.v;
    }

    f32x4 oacc[8];
    __builtin_amdgcn_s_setprio(1);
    #pragma unroll
    for (int dt=0;dt<8;dt++){
      oacc[dt] = f32x4{0.f,0.f,0.f,0.f};
      int row = dt*16 + l15;
      #pragma unroll
      for (int kk=0;kk<8;kk++){
        s16x8 a = *(const s16x8*)(Vb_ + row*512 + (((kk*4+g) ^ (row&7))*16));
        oacc[dt] = __builtin_amdgcn_mfma_f32_16x16x32_bf16(a, pb[kk], oacc[dt], 0,0,0);
      }
    }
    __builtin_amdgcn_s_setprio(0);

    #pragma unroll
    for (int dt=0;dt<8;dt++){
      u16x4 u;
      #pragma unroll
      for (int r=0;r<4;r++) u[r] = f2bf(oacc[dt][r]);
      *(u16x4*)(AO + ((size_t)b*NS + q)*ND + h*NHD + dt*16 + g*4) = u;
    }
  };

  pass(0, true);
  pass(1, false);
}

extern "C" void kernel_launch(void* const* d_in, const int* in_sizes, int n_in,
                              void* d_out, int out_size, void* d_ws, size_t ws_size,
                              hipStream_t stream)
{
  const float* q  = (const float*)d_in[0];
  const float* k  = (const float*)d_in[1];
  const float* v  = (const float*)d_in[2];
  const int* mask = (const int*)d_in[3];
  const float* Wq = (const float*)d_in[4];
  const float* bq = (const float*)d_in[5];
  const float* Wk = (const float*)d_in[6];
  const float* bk = (const float*)d_in[7];
  const float* Wv = (const float*)d_in[8];
  const float* bv = (const float*)d_in[9];
  const float* Wo = (const float*)d_in[10];
  const float* bo = (const float*)d_in[11];
  const float* bias_table = (const float*)d_in[12];

  // workspace layout, max 336 MiB (< proven 352 MiB):
  //   Wob [0,8M)  wb [8M,16M)  tmp [16M,80M) (full-M bf16 activations)
  //   Qh [80M,144M)  Kh [144M,208M)  VT [208M,272M)  AO [272M,336M)
  char* ws = (char*)d_ws;
  unsigned short* Wob = (unsigned short*)(ws + 0);
  unsigned short* wb  = (unsigned short*)(ws + 8388608);
  unsigned short* tmp = (unsigned short*)(ws + 16777216);
  unsigned short* Qh  = (unsigned short*)(ws + 83886080);
  unsigned short* Kh  = (unsigned short*)(ws + 150994944);
  unsigned short* VT  = (unsigned short*)(ws + 218103808);
  unsigned short* AO  = (unsigned short*)(ws + 285212672);

  hipFuncSetAttribute((const void*)gemm256<0>, hipFuncAttributeMaxDynamicSharedMemorySize, 131072);
  hipFuncSetAttribute((const void*)gemm256<1>, hipFuncAttributeMaxDynamicSharedMemorySize, 131072);
  hipFuncSetAttribute((const void*)gemm256<2>, hipFuncAttributeMaxDynamicSharedMemorySize, 131072);

  wconv<<<2048,256,0,stream>>>(Wo, Wob, 524288);

  const float* acts[3]  = {q, k, v};
  const float* wgt[3]   = {Wq, Wk, Wv};
  const float* bia[3]   = {bq, bk, bv};
  unsigned short* outs[3] = {Qh, Kh, VT};

  for (int x = 0; x < 3; ++x) {
    wconv<<<2048,256,0,stream>>>(wgt[x], wb, 524288);
    wconv<<<16384,256,0,stream>>>(acts[x], tmp, 4194304);
    if (x < 2)
      gemm256<0><<<512,512,131072,stream>>>(tmp, wb, bia[x], outs[x], 0);
    else
      gemm256<1><<<512,512,131072,stream>>>(tmp, wb, bia[x], outs[x], 0);
  }

  attn_fused2<<<1024,512,0,stream>>>(Qh,Kh,VT,mask,bias_table,AO);
  gemm256<2><<<512,512,131072,stream>>>(AO,Wob,bo,(float*)d_out,0);
}

// Round 9
// 745.593 us; speedup vs baseline: 1.0675x; 1.0438x over previous
//
#include <hip/hip_runtime.h>
#include <hip/hip_bf16.h>

typedef __attribute__((ext_vector_type(4))) float f32x4;
typedef __attribute__((ext_vector_type(8))) short s16x8;
typedef __attribute__((ext_vector_type(4))) unsigned short u16x4;
typedef __attribute__((ext_vector_type(8))) unsigned short u16x8;
typedef __attribute__((ext_vector_type(4))) int i32x4;

#define NB 64
#define NS 256
#define ND 2048
#define NH 16
#define NHD 128

__device__ __forceinline__ unsigned short f2bf(float f){
  unsigned int u = __float_as_uint(f);
  u += 0x7fffu + ((u >> 16) & 1u);
  return (unsigned short)(u >> 16);
}

__device__ __forceinline__ void gload16(const void* g, void* l){
  __builtin_amdgcn_global_load_lds(
    (const __attribute__((address_space(1))) unsigned int*)g,
    (__attribute__((address_space(3))) unsigned int*)l, 16, 0, 0);
}

#define SBAR()  __builtin_amdgcn_sched_barrier(0)
#define BARRIER() do{ SBAR(); __builtin_amdgcn_s_barrier(); SBAR(); }while(0)
#define WAIT_LGKM0() do{ asm volatile("s_waitcnt lgkmcnt(0)" ::: "memory"); SBAR(); }while(0)
#define WAIT_VM0()   do{ asm volatile("s_waitcnt vmcnt(0)"   ::: "memory"); SBAR(); }while(0)
#define WAIT_VM4()   do{ asm volatile("s_waitcnt vmcnt(4)"   ::: "memory"); SBAR(); }while(0)
#define WAIT_VM8()   do{ asm volatile("s_waitcnt vmcnt(8)"   ::: "memory"); SBAR(); }while(0)

// ---------------- fp32 -> bf16 conversion ----------------
__global__ __launch_bounds__(256) void wconv(const float* __restrict__ s,
                                             unsigned short* __restrict__ d, int n8){
  int i = blockIdx.x*256 + threadIdx.x;
  if (i >= n8) return;
  f32x4 a = *(const f32x4*)(s + (size_t)i*8);
  f32x4 b = *(const f32x4*)(s + (size_t)i*8 + 4);
  u16x8 u;
  #pragma unroll
  for (int r=0;r<4;r++){ u[r]=f2bf(a[r]); u[4+r]=f2bf(b[r]); }
  *(u16x8*)(d + (size_t)i*8) = u;
}

// ---------------- 256x256 GEMM, m201-style fine-interleaved pipeline ----------------
// Round-9: ONE half-tile (2 gloads) staged per phase (m196: the fine
// ds_read ∥ G::load ∥ MFMA interleave IS the lever; burst staging hurts).
// Half-iteration H_k computes tile T from dbuf d=k&1. Dead-region proof:
//   d's B region: last read P2 (qb=1); every wave passes P2's 2nd barrier only
//     after its lgkmcnt(0) -> after that barrier ALL B reads landed -> P3/P4
//     may stage hB0/hB1(T+2) into d.
//   d^1's A region: last read at H_{k-1} P3; its end barrier long past -> P1/P2
//     may stage hA0/hA1(T+1) into d^1.
// Boundary wait vmcnt(4): outstanding = the 2 hB stages just issued (P3,P4);
// the 2 hA stages of tile T+1 (issued P1,P2) are forced to land. Never 0
// in-loop; single vmcnt(0) at H30.
template<int OUTMODE>
__global__ __launch_bounds__(512, 2) void gemm256(
    const unsigned short* __restrict__ A, const unsigned short* __restrict__ Bw,
    const float* __restrict__ bias, void* __restrict__ Out, int m_base)
{
  extern __shared__ __attribute__((aligned(16))) char ldsb[];  // 131072 B
  const int tid  = threadIdx.x;
  const int lane = tid & 63, wid = tid >> 6;
  const int g = lane >> 4, l15 = lane & 15;
  const int wm = wid >> 2, wn = wid & 3;

  const int nwg = gridDim.x, bid = blockIdx.x;
  const int swz = (bid & 7) * (nwg >> 3) + (bid >> 3);
  const int mt = swz >> 3, nt = swz & 7;
  const int m0 = mt*256, n0 = nt*256;

  const int srow_l = tid >> 3;
  const int scol   = (((tid & 7) ^ (srow_l & 7)) * 8);
  const unsigned short* gsrc[4];
  gsrc[0] = A  + (size_t)(m0 +       srow_l)*ND + scol;   // hA0: A rows [0,128)
  gsrc[1] = A  + (size_t)(m0 + 128 + srow_l)*ND + scol;   // hA1: A rows [128,256)
  gsrc[2] = Bw + (size_t)(n0 +       srow_l)*ND + scol;   // hB0: B rows [0,128)
  gsrc[3] = Bw + (size_t)(n0 + 128 + srow_l)*ND + scol;   // hB1: B rows [128,256)

#define STAGE(buf, p, kt) do{ \
    const unsigned short* s_ = gsrc[p] + (kt); \
    char* d_ = ldsb + (buf)*65536 + ((p)>>1)*32768 + ((p)&1)*16384 + tid*16; \
    gload16(s_, d_); gload16(s_ + (size_t)64*ND, d_ + 8192); }while(0)

#define RD_A(buf, qa) do{ \
    _Pragma("unroll") for (int i_=0;i_<4;i_++){ \
      int hr = (qa)*64 + i_*16 + l15; \
      const char* p_ = ldsb + (buf)*65536 + wm*16384 + hr*128; \
      _Pragma("unroll") for (int ks_=0;ks_<2;ks_++) \
        av[i_][ks_] = *(const s16x8*)(p_ + (((ks_*4+g) ^ (hr&7))*16)); } }while(0)

#define RD_B(buf, dst, qb) do{ \
    _Pragma("unroll") for (int j_=0;j_<2;j_++){ \
      int hc = (wn&1)*64 + (qb)*32 + j_*16 + l15; \
      const char* p_ = ldsb + (buf)*65536 + 32768 + (wn>>1)*16384 + hc*128; \
      _Pragma("unroll") for (int ks_=0;ks_<2;ks_++) \
        dst[j_][ks_] = *(const s16x8*)(p_ + (((ks_*4+g) ^ (hc&7))*16)); } }while(0)

#define MFMA_PH(qa, qb, bv) do{ \
    __builtin_amdgcn_s_setprio(1); \
    _Pragma("unroll") for (int i_=0;i_<4;i_++) \
      _Pragma("unroll") for (int j_=0;j_<2;j_++) \
        _Pragma("unroll") for (int ks_=0;ks_<2;ks_++) \
          acc[(qa)*4+i_][(qb)*2+j_] = __builtin_amdgcn_mfma_f32_16x16x32_bf16( \
              av[i_][ks_], bv[j_][ks_], acc[(qa)*4+i_][(qb)*2+j_], 0,0,0); \
    __builtin_amdgcn_s_setprio(0); }while(0)

// Half-iteration. ktA: K-offset of tile T+1 (hA stages -> dbuf d^1), or -1.
// ktB: K-offset of tile T+2 (hB stages -> dbuf d), or -1.
// wmode: 0 = vmcnt(4)+barrier, 1 = vmcnt(0)+barrier, -1 = none.
#define HALF(d, ktA, ktB, wmode) do{ \
    RD_A(d,0); RD_B(d,bva,0); \
    if ((ktA)>=0) STAGE((d)^1, 0, ktA); \
    BARRIER(); WAIT_LGKM0(); \
    MFMA_PH(0,0,bva); \
    BARRIER(); \
    RD_B(d,bvb,1); \
    if ((ktA)>=0) STAGE((d)^1, 1, ktA); \
    BARRIER(); WAIT_LGKM0(); \
    MFMA_PH(0,1,bvb); \
    BARRIER(); \
    RD_A(d,1); \
    if ((ktB)>=0) STAGE(d, 2, ktB); \
    BARRIER(); WAIT_LGKM0(); \
    MFMA_PH(1,0,bva); \
    BARRIER(); \
    if ((ktB)>=0) STAGE(d, 3, ktB); \
    MFMA_PH(1,1,bvb); \
    if ((wmode)==0){ WAIT_VM4(); BARRIER(); } \
    else if ((wmode)==1){ WAIT_VM0(); BARRIER(); } \
  }while(0)

  f32x4 acc[8][4];
  s16x8 av[4][2], bva[2][2], bvb[2][2];

  // prologue: T0 fully -> dbuf0; hB0,hB1 of T1 -> dbuf1 (hA of T1 staged in H0)
  STAGE(0,0,0); STAGE(0,1,0); STAGE(0,2,0); STAGE(0,3,0);
  STAGE(1,2,64); STAGE(1,3,64);
  #pragma unroll
  for (int i=0;i<8;i++)
    #pragma unroll
    for (int j=0;j<4;j++) acc[i][j] = f32x4{0.f,0.f,0.f,0.f};
  WAIT_VM4();     // T0 landed; hB(T1) may stay in flight
  BARRIER();

  for (int t = 0; t < 15; ++t) {
    HALF(0, (2*t+1)*64, (2*t+2)*64, 0);   // tile 2t   : hA(2t+1), hB(2t+2)
    HALF(1, (2*t+2)*64, (2*t+3)*64, 0);   // tile 2t+1 : hA(2t+2), hB(2t+3)
  }
  HALF(0, 31*64, -1, 1);                  // tile 30: hA(31); drain all
  HALF(1, -1, -1, -1);                    // tile 31: no stages, no wait

  #pragma unroll
  for (int jx=0;jx<4;jx++){
    int n = n0 + wn*64 + ((jx>>1)<<5) + ((jx&1)<<4) + l15;
    float bj = bias[n];
    #pragma unroll
    for (int i=0;i<8;i++){
      int mb = m_base + m0 + wm*128 + ((i>>2)<<6) + ((i&3)<<4) + g*4;
      if (OUTMODE == 2){
        float* O = (float*)Out;
        #pragma unroll
        for (int r=0;r<4;r++) O[(size_t)(mb+r)*ND + n] = acc[i][jx][r] + bj;
      } else if (OUTMODE == 0){
        unsigned short* O = (unsigned short*)Out;
        int bb = mb >> 8, h = n >> 7, d = n & 127, s0 = mb & 255;
        #pragma unroll
        for (int r=0;r<4;r++)
          O[(((size_t)bb*NH + h)*NS + s0 + r)*NHD + d] = f2bf(acc[i][jx][r] + bj);
      } else {
        unsigned short* O = (unsigned short*)Out;
        int bb = mb >> 8, h = n >> 7, d = n & 127, s0 = mb & 255;
        u16x4 u;
        #pragma unroll
        for (int r=0;r<4;r++) u[r] = f2bf(acc[i][jx][r] + bj);
        *(u16x4*)(O + (((size_t)bb*NH + h)*NHD + d)*NS + s0) = u;
      }
    }
  }
#undef STAGE
#undef RD_A
#undef RD_B
#undef MFMA_PH
#undef HALF
}

// ---------------- fused attention v2 (unchanged from round 6) ----------------
__global__ __launch_bounds__(512, 1) void attn_fused2(
  const unsigned short* __restrict__ Qh, const unsigned short* __restrict__ Kh,
  const unsigned short* __restrict__ VT, const int* __restrict__ mask,
  const float* __restrict__ bias_table, unsigned short* __restrict__ AO)
{
  __shared__ unsigned short Klds[256*128];
  __shared__ unsigned short Vlds[128*256];
  char* Kb_ = (char*)Klds; char* Vb_ = (char*)Vlds;
  const int bh = blockIdx.x, b = bh >> 4, h = bh & 15;
  const int tid = threadIdx.x, lane = tid & 63, w = tid >> 6;
  const int g = lane >> 4, l15 = lane & 15;

  {
    const unsigned short* Ksrc = Kh + (size_t)bh*NS*NHD;
    int r0 = tid >> 4, sl = tid & 15;
    #pragma unroll
    for (int c=0;c<8;c++){
      int row = c*32 + r0;
      gload16(Ksrc + (size_t)row*NHD + ((sl ^ (row&7))*8), Kb_ + c*8192 + tid*16);
    }
  }
  {
    const unsigned short* Vsrc = VT + (size_t)bh*NHD*NS;
    int r0 = tid >> 5, sl = tid & 31;
    #pragma unroll
    for (int c=0;c<8;c++){
      int row = c*16 + r0;
      gload16(Vsrc + (size_t)row*NS + ((sl ^ (row&7))*8), Vb_ + c*8192 + tid*16);
    }
  }
  WAIT_VM8();
  BARRIER();

  const float scale = 0.08838834764831845f;
  const int* mrow = mask + b*NS;
  const int s0l = l15 + ((g&1)<<5), s1l = s0l + 16;
  const int sel = g >> 1;

  auto pass = [&](int p, bool wait_v){
    const int q = w*32 + p*16 + l15;
    const unsigned short* Qrow = Qh + ((size_t)bh*NS + q)*NHD;
    s16x8 bq[4];
    #pragma unroll
    for (int kk=0;kk<4;kk++) bq[kk] = *(const s16x8*)(Qrow + kk*32 + g*8);

    f32x4 c[16];
    __builtin_amdgcn_s_setprio(1);
    #pragma unroll
    for (int kb=0;kb<16;kb++){
      c[kb] = f32x4{0.f,0.f,0.f,0.f};
      int row = kb*16 + l15;
      #pragma unroll
      for (int kk=0;kk<4;kk++){
        s16x8 a = *(const s16x8*)(Kb_ + row*256 + (((kk*4+g) ^ (row&7))*16));
        c[kb] = __builtin_amdgcn_mfma_f32_16x16x32_bf16(a, bq[kk], c[kb], 0,0,0);
      }
    }
    __builtin_amdgcn_s_setprio(0);

    const float* brow = bias_table + ((size_t)h*NS + q)*NS;
    float mx = -3.0e38f;
    #pragma unroll
    for (int kb=0;kb<16;kb++){
      f32x4 b4 = *(const f32x4*)(brow + kb*16 + g*4);
      i32x4 m4 = *(const i32x4*)(mrow + kb*16 + g*4);
      #pragma unroll
      for (int r=0;r<4;r++){
        float val = (m4[r] != 0) ? (c[kb][r]*scale + b4[r]) : -3.0e38f;
        c[kb][r] = val;
        mx = fmaxf(mx, val);
      }
    }
    mx = fmaxf(mx, __shfl_xor(mx, 16));
    mx = fmaxf(mx, __shfl_xor(mx, 32));
    float sum = 0.f;
    #pragma unroll
    for (int kb=0;kb<16;kb++)
      #pragma unroll
      for (int r=0;r<4;r++){
        float pv = __expf(c[kb][r] - mx);
        c[kb][r] = pv; sum += pv;
      }
    sum += __shfl_xor(sum, 16);
    sum += __shfl_xor(sum, 32);
    float inv = 1.f / sum;

    unsigned int pk[16][2];
    #pragma unroll
    for (int kb=0;kb<16;kb++){
      pk[kb][0] = (unsigned int)f2bf(c[kb][0]*inv) | ((unsigned int)f2bf(c[kb][1]*inv) << 16);
      pk[kb][1] = (unsigned int)f2bf(c[kb][2]*inv) | ((unsigned int)f2bf(c[kb][3]*inv) << 16);
    }

    if (wait_v){ WAIT_VM0(); BARRIER(); }

    s16x8 pb[8];
    #pragma unroll
    for (int kk=0;kk<8;kk++){
      unsigned int e0 = (unsigned int)__shfl((int)pk[2*kk][0],   s0l);
      unsigned int e1 = (unsigned int)__shfl((int)pk[2*kk][1],   s0l);
      unsigned int e2 = (unsigned int)__shfl((int)pk[2*kk][0],   s1l);
      unsigned int e3 = (unsigned int)__shfl((int)pk[2*kk][1],   s1l);
      unsigned int o0 = (unsigned int)__shfl((int)pk[2*kk+1][0], s0l);
      unsigned int o1 = (unsigned int)__shfl((int)pk[2*kk+1][1], s0l);
      unsigned int o2 = (unsigned int)__shfl((int)pk[2*kk+1][0], s1l);
      unsigned int o3 = (unsigned int)__shfl((int)pk[2*kk+1][1], s1l);
      union { unsigned int wd[4]; s16x8 v; } u_;
      u_.wd[0] = sel ? o0 : e0; u_.wd[1] = sel ? o1 : e1;
      u_.wd[2] = sel ? o2 : e2; u_.wd[3] = sel ? o3 : e3;
      pb[kk] = u_.v;
    }

    f32x4 oacc[8];
    __builtin_amdgcn_s_setprio(1);
    #pragma unroll
    for (int dt=0;dt<8;dt++){
      oacc[dt] = f32x4{0.f,0.f,0.f,0.f};
      int row = dt*16 + l15;
      #pragma unroll
      for (int kk=0;kk<8;kk++){
        s16x8 a = *(const s16x8*)(Vb_ + row*512 + (((kk*4+g) ^ (row&7))*16));
        oacc[dt] = __builtin_amdgcn_mfma_f32_16x16x32_bf16(a, pb[kk], oacc[dt], 0,0,0);
      }
    }
    __builtin_amdgcn_s_setprio(0);

    #pragma unroll
    for (int dt=0;dt<8;dt++){
      u16x4 u;
      #pragma unroll
      for (int r=0;r<4;r++) u[r] = f2bf(oacc[dt][r]);
      *(u16x4*)(AO + ((size_t)b*NS + q)*ND + h*NHD + dt*16 + g*4) = u;
    }
  };

  pass(0, true);
  pass(1, false);
}

extern "C" void kernel_launch(void* const* d_in, const int* in_sizes, int n_in,
                              void* d_out, int out_size, void* d_ws, size_t ws_size,
                              hipStream_t stream)
{
  const float* q  = (const float*)d_in[0];
  const float* k  = (const float*)d_in[1];
  const float* v  = (const float*)d_in[2];
  const int* mask = (const int*)d_in[3];
  const float* Wq = (const float*)d_in[4];
  const float* bq = (const float*)d_in[5];
  const float* Wk = (const float*)d_in[6];
  const float* bk = (const float*)d_in[7];
  const float* Wv = (const float*)d_in[8];
  const float* bv = (const float*)d_in[9];
  const float* Wo = (const float*)d_in[10];
  const float* bo = (const float*)d_in[11];
  const float* bias_table = (const float*)d_in[12];

  // workspace layout, max 336 MiB (< proven 352 MiB):
  //   Wob [0,8M)  wb [8M,16M)  tmp [16M,80M) (full-M bf16 activations)
  //   Qh [80M,144M)  Kh [144M,208M)  VT [208M,272M)  AO [272M,336M)
  char* ws = (char*)d_ws;
  unsigned short* Wob = (unsigned short*)(ws + 0);
  unsigned short* wb  = (unsigned short*)(ws + 8388608);
  unsigned short* tmp = (unsigned short*)(ws + 16777216);
  unsigned short* Qh  = (unsigned short*)(ws + 83886080);
  unsigned short* Kh  = (unsigned short*)(ws + 150994944);
  unsigned short* VT  = (unsigned short*)(ws + 218103808);
  unsigned short* AO  = (unsigned short*)(ws + 285212672);

  hipFuncSetAttribute((const void*)gemm256<0>, hipFuncAttributeMaxDynamicSharedMemorySize, 131072);
  hipFuncSetAttribute((const void*)gemm256<1>, hipFuncAttributeMaxDynamicSharedMemorySize, 131072);
  hipFuncSetAttribute((const void*)gemm256<2>, hipFuncAttributeMaxDynamicSharedMemorySize, 131072);

  wconv<<<2048,256,0,stream>>>(Wo, Wob, 524288);

  const float* acts[3]  = {q, k, v};
  const float* wgt[3]   = {Wq, Wk, Wv};
  const float* bia[3]   = {bq, bk, bv};
  unsigned short* outs[3] = {Qh, Kh, VT};

  for (int x = 0; x < 3; ++x) {
    wconv<<<2048,256,0,stream>>>(wgt[x], wb, 524288);
    wconv<<<16384,256,0,stream>>>(acts[x], tmp, 4194304);
    if (x < 2)
      gemm256<0><<<512,512,131072,stream>>>(tmp, wb, bia[x], outs[x], 0);
    else
      gemm256<1><<<512,512,131072,stream>>>(tmp, wb, bia[x], outs[x], 0);
  }

  attn_fused2<<<1024,512,0,stream>>>(Qh,Kh,VT,mask,bias_table,AO);
  gemm256<2><<<512,512,131072,stream>>>(AO,Wob,bo,(float*)d_out,0);
}